// Round 3
// baseline (1266.436 us; speedup 1.0000x reference)
//
#include <hip/hip_runtime.h>

// Problem constants
namespace {
constexpr int Bc = 128, Lc = 36, Vc = 36, Dc = 512, KDc = 300, KVc = 112, Qc = 36, Hc = 512;
constexpr int ROWS = Bc * Lc * Vc;     // 165888 rows of (b,l,j)
constexpr int BLn  = Bc * Lc;          // 4608
constexpr int SLOT = Bc * Qc * Qc;     // 165888
constexpr float SCALE = 1.0f / 6.0f;   // 36^-0.5
}

__device__ __forceinline__ float wave_sum(float v) {
  #pragma unroll
  for (int off = 32; off > 0; off >>= 1) v += __shfl_xor(v, off, 64);
  return v;
}
__device__ __forceinline__ float wave_max(float v) {
  #pragma unroll
  for (int off = 32; off > 0; off >>= 1) v = fmaxf(v, __shfl_xor(v, off, 64));
  return v;
}
__device__ __forceinline__ float sigmoidf_(float x) { return 1.f / (1.f + __expf(-x)); }
__device__ __forceinline__ float dot4_(float4 a, float4 b) {
  return fmaf(a.x, b.x, fmaf(a.y, b.y, fmaf(a.z, b.z, a.w * b.w)));
}

// csum[b][j][d] = sum_l ctx[b][l][j][d]
__global__ __launch_bounds__(256) void csum_kernel(const float* __restrict__ ctx, float* __restrict__ csum) {
  int tid = blockIdx.x * 256 + threadIdx.x;   // < B*V*D
  int b  = tid / (Vc * Dc);
  int jd = tid % (Vc * Dc);
  const float* p = ctx + (size_t)b * Lc * Vc * Dc + jd;
  float s = 0.f;
  #pragma unroll
  for (int l = 0; l < Lc; ++l) s += p[(size_t)l * (Vc * Dc)];
  csum[tid] = s;
}

// kd[bl][q] = sum_c det[bl][c] * Wk[q][512+c]
__global__ void kd_kernel(const float* __restrict__ det, const float* __restrict__ Wk,
                          float* __restrict__ kd) {
  __shared__ float ds[KDc];
  int bl = blockIdx.x; int t = threadIdx.x;
  for (int c = t; c < KDc; c += 64) ds[c] = det[(size_t)bl * KDc + c];
  __syncthreads();
  if (t < Qc) {
    const float* w = Wk + (size_t)t * 812 + 512;
    float acc = 0.f;
    #pragma unroll 4
    for (int c = 0; c < KDc; ++c) acc = fmaf(ds[c], w[c], acc);
    kd[(size_t)bl * Qc + t] = acc;
  }
}

// kT[b][q][lj] = sum_{d<512} ctx_flat[b*1296+lj][d]*Wk[q][d] + kd[(b*36+l)][q]
// transposed write so mega's dot phase reads coalesced over lj.
__global__ __launch_bounds__(256) void k_gemm(const float* __restrict__ A, const float* __restrict__ Wk,
                       const float* __restrict__ kd, float* __restrict__ kout) {
  __shared__ __align__(16) float As[32 * 260];
  __shared__ __align__(16) float Bs[32 * 48];
  int t = threadIdx.x;
  int rb = blockIdx.x * 256;
  int tr = t & 63, tc = t >> 6;
  float acc[4][9];
  #pragma unroll
  for (int i = 0; i < 4; ++i)
    #pragma unroll
    for (int c = 0; c < 9; ++c) acc[i][c] = 0.f;

  for (int d0 = 0; d0 < 512; d0 += 32) {
    #pragma unroll
    for (int jj = 0; jj < 8; ++jj) {
      int idx = t + jj * 256;
      int kkb = (idx & 7) * 4, r = idx >> 3;
      const float4 v = *(const float4*)(A + (size_t)(rb + r) * 512 + d0 + kkb);
      As[(kkb + 0) * 260 + r] = v.x;
      As[(kkb + 1) * 260 + r] = v.y;
      As[(kkb + 2) * 260 + r] = v.z;
      As[(kkb + 3) * 260 + r] = v.w;
    }
    for (int idx = t; idx < 32 * 36; idx += 256) {
      int kk = idx / 36, c = idx % 36;
      Bs[kk * 48 + (c / 9) * 12 + (c % 9)] = Wk[(size_t)c * 812 + d0 + kk];
    }
    __syncthreads();
    #pragma unroll
    for (int kk = 0; kk < 32; ++kk) {
      const float4 a  = *(const float4*)&As[kk * 260 + tr * 4];
      const float* bp = &Bs[kk * 48 + tc * 12];
      const float4 b0 = *(const float4*)bp;
      const float4 b1 = *(const float4*)(bp + 4);
      const float  b8 = bp[8];
      const float av[4] = {a.x, a.y, a.z, a.w};
      const float bv[9] = {b0.x, b0.y, b0.z, b0.w, b1.x, b1.y, b1.z, b1.w, b8};
      #pragma unroll
      for (int i = 0; i < 4; ++i)
        #pragma unroll
        for (int c = 0; c < 9; ++c) acc[i][c] = fmaf(av[i], bv[c], acc[i][c]);
    }
    __syncthreads();
  }
  #pragma unroll
  for (int i = 0; i < 4; ++i) {
    int row = rb + tr * 4 + i;
    int bq = row / 1296;       // batch
    int lj = row % 1296;
    int bl = row / 36;
    #pragma unroll
    for (int c = 0; c < 9; ++c) {
      int q = tc * 9 + c;
      kout[((size_t)bq * 36 + q) * 1296 + lj] = acc[i][c] + kd[(size_t)bl * 36 + q];
    }
  }
}

// generic small GEMM vs Wih: outp[row][c] = sum_k A[row*lda+k] * Wih[c*624 + k0 + k]
__global__ __launch_bounds__(256) void prew_gemm(const float* __restrict__ A, int lda, int K, int k0,
                                                 const float* __restrict__ Wih, float* __restrict__ outp) {
  __shared__ __align__(16) float As[16 * 68];   // [k][row]
  __shared__ __align__(16) float Bs[16 * 112];  // [k][col grouped 28]
  int t = threadIdx.x;
  int rb = blockIdx.x * 64;
  int tr = t & 63, tc = t >> 6;      // tc in 0..3, 27 cols each
  float acc[27];
  #pragma unroll
  for (int c = 0; c < 27; ++c) acc[c] = 0.f;

  for (int kk0 = 0; kk0 < K; kk0 += 16) {
    {
      int r = t >> 2, kq = (t & 3) * 4;
      const float4 v = *(const float4*)(A + (size_t)(rb + r) * lda + kk0 + kq);
      As[(kq + 0) * 68 + r] = v.x;
      As[(kq + 1) * 68 + r] = v.y;
      As[(kq + 2) * 68 + r] = v.z;
      As[(kq + 3) * 68 + r] = v.w;
    }
    for (int idx = t; idx < 16 * 108; idx += 256) {
      int k = idx / 108, c = idx % 108;
      Bs[k * 112 + (c / 27) * 28 + (c % 27)] = Wih[(size_t)c * 624 + k0 + kk0 + k];
    }
    __syncthreads();
    #pragma unroll
    for (int k = 0; k < 16; ++k) {
      const float a = As[k * 68 + tr];
      const float* bp = &Bs[k * 112 + tc * 28];
      float bv[27];
      #pragma unroll
      for (int c4 = 0; c4 < 6; ++c4) {
        float4 b4 = *(const float4*)(bp + c4 * 4);
        bv[c4 * 4 + 0] = b4.x; bv[c4 * 4 + 1] = b4.y; bv[c4 * 4 + 2] = b4.z; bv[c4 * 4 + 3] = b4.w;
      }
      bv[24] = bp[24]; bv[25] = bp[25]; bv[26] = bp[26];
      #pragma unroll
      for (int c = 0; c < 27; ++c) acc[c] = fmaf(a, bv[c], acc[c]);
    }
    __syncthreads();
  }
  int row = rb + tr;
  #pragma unroll
  for (int c = 0; c < 27; ++c)
    outp[(size_t)row * 108 + tc * 27 + c] = acc[c];
}

// ===================== MEGA KERNEL (1024 threads, 16 waves, coalesced kT) =====================
__global__ __launch_bounds__(1024) void mega_kernel(
    const float* __restrict__ pano, const float* __restrict__ kmatT,
    const float* __restrict__ cw,   const float* __restrict__ gknw,
    const float* __restrict__ Wq,   const float* __restrict__ Whh,
    const float* __restrict__ bih,  const float* __restrict__ bhh,
    const float* __restrict__ lsg,  const float* __restrict__ lsb,
    const float* __restrict__ lfg,  const float* __restrict__ lfb,
    const float* __restrict__ W1,   const float* __restrict__ b1,
    const float* __restrict__ W2,   const float* __restrict__ b2,
    float* __restrict__ out) {
  const int b = blockIdx.x;
  const int t = threadIdx.x;
  const int wv = t >> 6, lane = t & 63;

  // ~103 KB LDS, 1 block/CU, 16 waves (4/SIMD)
  __shared__ __align__(16) float s0[36 * 40], s1[36 * 40];  // slots dbuf
  __shared__ float at[36 * 36];
  __shared__ float dt_s[36 * 36];
  __shared__ __align__(16) float cw_s[36 * 108], gk_s[36 * 108];
  __shared__ __align__(16) float whh_s[108 * 44];
  __shared__ __align__(16) float ff_s[36 * 40];
  __shared__ float ls16[16 * 37];
  __shared__ float qred[36];
  __shared__ float qs[36];
  __shared__ __align__(16) float mid_s[36 * 132];           // mlp1 chunk (128 wide)
  __shared__ __align__(16) float b1_s[512];
  __shared__ float bih_s[108], bhh_s[108];

  // ---- one-time staging ----
  for (int q4 = t; q4 < 972; q4 += 1024) {
    *(float4*)&cw_s[q4 * 4] = *(const float4*)(cw   + (size_t)b * 3888 + q4 * 4);
    *(float4*)&gk_s[q4 * 4] = *(const float4*)(gknw + (size_t)b * 3888 + q4 * 4);
  }
  for (int idx = t; idx < 3888; idx += 1024)
    whh_s[(idx / 36) * 44 + idx % 36] = Whh[idx];
  for (int idx = t; idx < 1296; idx += 1024)
    s0[(idx / 36) * 40 + idx % 36] = pano[idx];
  if (t < 512) b1_s[t] = b1[t];
  if (t < 108) { bih_s[t] = bih[t]; bhh_s[t] = bhh[t]; }
  float gv = 0.f, bv = 0.f, fg = 0.f, fb = 0.f, b2v = 0.f;
  if (lane < 36) { gv = lsg[lane]; bv = lsb[lane]; fg = lfg[lane]; fb = lfb[lane]; b2v = b2[lane]; }
  const float* kbT = kmatT + (size_t)b * 36 * 1296;
  __syncthreads();

  for (int it = 0; it < 3; ++it) {
    float* cur = (it == 1) ? s1 : s0;
    float* nxt = (it == 1) ? s0 : s1;
    float* aout = out + SLOT + (size_t)it * SLOT + (size_t)b * 1296;

    // ---- phase 1: LN(slots) rows over 16 waves; qsum = (sum_i LN_i) @ Wq^T ----
    float lnsum = 0.f;
    #pragma unroll
    for (int ii = 0; ii < 3; ++ii) {
      int i = wv + 16 * ii;
      bool act = (i < 36) && (lane < 36);
      float x = act ? cur[i * 40 + lane] : 0.f;
      float mu = wave_sum(x) * (1.f / 36.f);
      float d = x - mu;
      float var = wave_sum(act ? d * d : 0.f) * (1.f / 36.f);
      if (act) lnsum += d * rsqrtf(var + 1e-5f) * gv + bv;
    }
    if (lane < 36) ls16[wv * 37 + lane] = lnsum;
    __syncthreads();
    if (t < 36) {
      float l0 = 0.f;
      #pragma unroll
      for (int w = 0; w < 16; ++w) l0 += ls16[w * 37 + t];
      qred[t] = l0;
    }
    __syncthreads();
    if (t < 36) {
      float acc = 0.f;
      #pragma unroll 9
      for (int e = 0; e < 36; ++e) acc = fmaf(qred[e], Wq[t * 36 + e], acc);
      qs[t] = acc;
    }
    __syncthreads();

    // ---- phase 2: dots via transposed kT (coalesced over lj), then softmax rows ----
    for (int lj = t; lj < 1296; lj += 1024) {
      const float* kp = kbT + lj;
      float acc = 0.f;
      #pragma unroll 9
      for (int q = 0; q < 36; ++q) acc = fmaf(kp[(size_t)q * 1296], qs[q], acc);
      dt_s[lj] = acc * SCALE;
    }
    __syncthreads();
    #pragma unroll
    for (int ii = 0; ii < 3; ++ii) {
      int l = wv + 16 * ii;
      if (l < 36) {
        float dv = (lane < 36) ? dt_s[l * 36 + lane] : -1e30f;
        float m = wave_max(dv);
        float e = (lane < 36) ? __expf(dv - m) : 0.f;
        float s = wave_sum(e);
        if (lane < 36) {
          float a = e / s;
          at[l * 36 + lane] = a;
          aout[(size_t)l * 36 + lane] = a;
        }
      }
    }
    __syncthreads();

    // ---- phase 3: fused gxmix + GRU, 1i x 2c tiles, 648 threads ----
    if (t < 648) {
      int i = t / 18, c0 = (t % 18) * 2;
      float ax[3][2], ah[3][2];
      #pragma unroll
      for (int g = 0; g < 3; ++g)
        #pragma unroll
        for (int cc = 0; cc < 2; ++cc) {
          ax[g][cc] = gk_s[i * 108 + g * 36 + c0 + cc] + bih_s[g * 36 + c0 + cc];
          ah[g][cc] = bhh_s[g * 36 + c0 + cc];
        }
      #pragma unroll 6
      for (int j = 0; j < 36; ++j) {
        float a0 = at[i * 36 + j];
        #pragma unroll
        for (int g = 0; g < 3; ++g)
          #pragma unroll
          for (int cc = 0; cc < 2; ++cc)
            ax[g][cc] = fmaf(a0, cw_s[j * 108 + g * 36 + c0 + cc], ax[g][cc]);
      }
      #pragma unroll
      for (int eq = 0; eq < 9; ++eq) {
        float4 hq = *(const float4*)&cur[i * 40 + eq * 4];
        #pragma unroll
        for (int g = 0; g < 3; ++g)
          #pragma unroll
          for (int cc = 0; cc < 2; ++cc)
            ah[g][cc] += dot4_(hq, *(const float4*)&whh_s[(g * 36 + c0 + cc) * 44 + eq * 4]);
      }
      #pragma unroll
      for (int cc = 0; cc < 2; ++cc) {
        int c = c0 + cc;
        float hp = cur[i * 40 + c];
        float rr = sigmoidf_(ax[0][cc] + ah[0][cc]);
        float zz = sigmoidf_(ax[1][cc] + ah[1][cc]);
        float nn = tanhf(ax[2][cc] + rr * ah[2][cc]);
        nxt[i * 40 + c] = (1.f - zz) * nn + zz * hp;
      }
    }
    __syncthreads();

    // ---- phase 4: LN-ff rows over 16 waves; snew init = hprime + b2 ----
    #pragma unroll
    for (int ii = 0; ii < 3; ++ii) {
      int i = wv + 16 * ii;
      if (i < 36) {
        float v = (lane < 36) ? nxt[i * 40 + lane] : 0.f;
        float mu = wave_sum(v) * (1.f / 36.f);
        float d = v - mu;
        float var = wave_sum((lane < 36) ? d * d : 0.f) * (1.f / 36.f);
        float rstd = rsqrtf(var + 1e-5f);
        if (lane < 36) {
          ff_s[i * 40 + lane] = d * rstd * fg + fb;
          nxt[i * 40 + lane] = v + b2v;
        }
      }
    }
    __syncthreads();

    // ---- phase 5: MLP, H chunked by 128; W1/W2 from global (L1/L2), mid in LDS ----
    float acc2[2] = {0.f, 0.f};
    for (int h0 = 0; h0 < 512; h0 += 128) {
      // mlp1: 2i x 4hh register tile, 576 threads
      if (t < 576) {
        int i0 = (t >> 5) * 2, hq = t & 31;
        int hh = h0 + hq * 4;
        float4 bq = *(const float4*)&b1_s[hh];
        float m[2][4] = {{bq.x, bq.y, bq.z, bq.w}, {bq.x, bq.y, bq.z, bq.w}};
        const float* w1p = W1 + (size_t)hh * 36;
        #pragma unroll
        for (int eq = 0; eq < 9; ++eq) {
          float4 f0 = *(const float4*)&ff_s[i0 * 40 + eq * 4];
          float4 f1 = *(const float4*)&ff_s[(i0 + 1) * 40 + eq * 4];
          #pragma unroll
          for (int c = 0; c < 4; ++c) {
            float4 wq4 = *(const float4*)(w1p + (size_t)c * 36 + eq * 4);
            m[0][c] += dot4_(f0, wq4);
            m[1][c] += dot4_(f1, wq4);
          }
        }
        #pragma unroll
        for (int r = 0; r < 2; ++r) {
          float4 o;
          o.x = fmaxf(m[r][0], 0.f); o.y = fmaxf(m[r][1], 0.f);
          o.z = fmaxf(m[r][2], 0.f); o.w = fmaxf(m[r][3], 0.f);
          *(float4*)&mid_s[(i0 + r) * 132 + hq * 4] = o;
        }
      }
      __syncthreads();
      // mlp2: 1i x 2c register tile, 648 threads, acc carried across chunks
      if (t < 648) {
        int i = t / 18, c0 = (t % 18) * 2;
        const float* w2a = W2 + (size_t)c0 * 512 + h0;
        const float* w2b = w2a + 512;
        #pragma unroll 8
        for (int kq = 0; kq < 32; ++kq) {
          float4 mm = *(const float4*)&mid_s[i * 132 + kq * 4];
          acc2[0] += dot4_(mm, *(const float4*)(w2a + kq * 4));
          acc2[1] += dot4_(mm, *(const float4*)(w2b + kq * 4));
        }
      }
      __syncthreads();  // mid consumed before next chunk overwrites
    }
    if (t < 648) {
      int i = t / 18, c0 = (t % 18) * 2;
      nxt[i * 40 + c0]     += acc2[0];
      nxt[i * 40 + c0 + 1] += acc2[1];
    }
    __syncthreads();
  }

  // final slots (after 3 iters result is in s1), vectorized store
  for (int v4 = t; v4 < 324; v4 += 1024) {
    int row = v4 / 9, q = v4 % 9;
    *(float4*)&out[(size_t)b * 1296 + row * 36 + q * 4] = *(const float4*)&s1[row * 40 + q * 4];
  }
}

extern "C" void kernel_launch(void* const* d_in, const int* in_sizes, int n_in,
                              void* d_out, int out_size, void* d_ws, size_t ws_size,
                              hipStream_t stream) {
  const float* ctx  = (const float*)d_in[1];
  const float* det  = (const float*)d_in[3];
  const float* knw  = (const float*)d_in[4];
  const float* pano = (const float*)d_in[5];
  const float* Wq   = (const float*)d_in[6];
  const float* Wk   = (const float*)d_in[7];
  const float* Wih  = (const float*)d_in[8];
  const float* Whh  = (const float*)d_in[9];
  const float* bih  = (const float*)d_in[10];
  const float* bhh  = (const float*)d_in[11];
  const float* lsg  = (const float*)d_in[12];
  const float* lsb  = (const float*)d_in[13];
  const float* lfg  = (const float*)d_in[14];
  const float* lfb  = (const float*)d_in[15];
  const float* W1   = (const float*)d_in[16];
  const float* b1   = (const float*)d_in[17];
  const float* W2   = (const float*)d_in[18];
  const float* b2   = (const float*)d_in[19];
  float* out = (float*)d_out;

  float* w = (float*)d_ws;
  float* kmatT = w; w += (size_t)ROWS * 36;     // 24 MB, layout [b][q][lj]
  float* csum  = w; w += (size_t)Bc * Vc * Dc;  // 9.4 MB
  float* kd    = w; w += (size_t)BLn * Qc;
  float* cw    = w; w += (size_t)BLn * 108;
  float* gknw  = w; w += (size_t)BLn * 108;

  csum_kernel<<<(Bc * Vc * Dc) / 256, 256, 0, stream>>>(ctx, csum);
  kd_kernel<<<BLn, 64, 0, stream>>>(det, Wk, kd);
  k_gemm<<<ROWS / 256, 256, 0, stream>>>(ctx, Wk, kd, kmatT);
  prew_gemm<<<72, 256, 0, stream>>>(csum, 512, 512, 0,   Wih, cw);    // cw  = csum @ Wih[:,:512]^T
  prew_gemm<<<72, 256, 0, stream>>>(knw,  112, 112, 512, Wih, gknw);  // gknw = knw @ Wih[:,512:]^T
  mega_kernel<<<Bc, 1024, 0, stream>>>(pano, kmatT, cw, gknw, Wq, Whh, bih, bhh,
                                       lsg, lsb, lfg, lfb, W1, b1, W2, b2, out);
}